// Round 1
// baseline (304.905 us; speedup 1.0000x reference)
//
#include <hip/hip_runtime.h>
#include <math.h>

#define EPS 1e-15f
#define BND (1.0f - 1e-7f)

constexpr int B = 64, S = 256, H = 768, D = 64, NEG = 4;
constexpr int NVEC = B + B + B * NEG; // 384 selected vectors

// Reduce across a 64-lane wave; result broadcast to all lanes.
__device__ inline float wave_red(float v) {
#pragma unroll
  for (int o = 32; o > 0; o >>= 1) v += __shfl_down(v, o, 64);
  return __shfl(v, 0, 64);
}

// One block per selected vector: scan one-hot mask row -> gather encoded row
// -> expmap0 -> mobius_matvec(W, .) -> write [D] vector to workspace.
__global__ __launch_bounds__(256) void gather_matvec_kernel(
    const float* __restrict__ encoded, const float* __restrict__ n_encoded,
    const float* __restrict__ mask1, const float* __restrict__ mask2,
    const float* __restrict__ mask_u_neg, const float* __restrict__ W,
    float* __restrict__ out_vecs) {
  __shared__ float xs[H];        // gathered raw row
  __shared__ float pm[4 * D];    // matvec partials (4 waves x D)
  __shared__ int s_idx;
  __shared__ float s_ssq;
  __shared__ float red[4];

  const int i = blockIdx.x;
  const int t = threadIdx.x;
  const int lane = t & 63, w = t >> 6;

  const float* mask;
  const float* src;
  if (i < B) {
    mask = mask1 + (size_t)i * S;
    src = encoded + (size_t)i * S * H;
  } else if (i < 2 * B) {
    mask = mask2 + (size_t)(i - B) * S;
    src = encoded + (size_t)(i - B) * S * H;
  } else {
    mask = mask_u_neg + (size_t)(i - 2 * B) * S;
    src = n_encoded + (size_t)(i - 2 * B) * S * H;
  }

  if (t == 0) s_idx = 0;
  __syncthreads();
  if (mask[t] > 0.5f) s_idx = t;  // one-hot: exactly one thread writes
  __syncthreads();
  const float* row = src + (size_t)s_idx * H;

  // Load row, accumulate sum of squares.
  float ssq = 0.f;
  for (int h = t; h < H; h += 256) {
    float v = row[h];
    xs[h] = v;
    ssq += v * v;
  }
  float wsum = wave_red(ssq);
  if (lane == 0) red[w] = wsum;
  __syncthreads();
  if (t == 0) s_ssq = red[0] + red[1] + red[2] + red[3];
  __syncthreads();

  const float n = sqrtf(s_ssq);
  const float n_cl = fmaxf(n, EPS);
  const float scale0 = tanhf(n_cl) / n_cl;  // expmap0 scale

  // Matvec: wave w sums h in [w*192, w*192+192), lane = output dim d.
  const int d = lane;
  const float* wrow = W + (size_t)d * H;
  float acc = 0.f;
  const int h0 = w * (H / 4);
#pragma unroll 4
  for (int h = h0; h < h0 + H / 4; ++h) acc += xs[h] * wrow[h];
  pm[w * D + d] = acc;
  __syncthreads();

  if (w == 0) {
    float mx = (pm[d] + pm[D + d] + pm[2 * D + d] + pm[3 * D + d]) * scale0;
    float mnsq = wave_red(mx * mx);
    float mn = fmaxf(sqrtf(mnsq), EPS);
    float xn = fmaxf(scale0 * n, EPS);            // ||expmap0(x)|| = tanh(n)
    float xn_c = fminf(fmaxf(xn, -BND), BND);
    float arg = mn / xn * atanhf(xn_c);
    float s1 = tanhf(arg) / mn;
    out_vecs[(size_t)i * D + d] = s1 * mx;
  }
}

// Single block: wave w handles rows b = w, w+16, ...; lane = dim d.
__global__ __launch_bounds__(1024) void loss_kernel(
    const float* __restrict__ vecs, float* __restrict__ out) {
  __shared__ float wsums[16];
  const int t = threadIdx.x, lane = t & 63, w = t >> 6;
  float local = 0.f;

  for (int b = w; b < B; b += 16) {
    const float* u = vecs + (size_t)b * D;
    const float* v = vecs + (size_t)(B + b) * D;
    const float ud = u[lane], vd = v[lane];
    const float u2 = wave_red(ud * ud);
    const float v2 = wave_red(vd * vd);
    const float uv = wave_red(ud * vd);
    const float e2 = wave_red((ud - vd) * (ud - vd));

    // dist(u, v) = 2*artanh(||mobius_add(-u, v)||)
    const float xy = -uv;
    const float co1 = 1.f + 2.f * xy + v2;
    const float co2 = 1.f - u2;
    const float numd = co1 * (-ud) + co2 * vd;
    const float nsq = wave_red(numd * numd);
    const float den = fmaxf(1.f + 2.f * xy + u2 * v2, EPS);
    const float r = sqrtf(nsq) / den;
    const float dsq = 2.f * atanhf(fminf(r, BND));
    const float exp_neg = expf(-dsq);

    float Z1 = 0.f;
    for (int nn = 0; nn < NEG; ++nn) {
      const float* un = vecs + (size_t)(2 * B + b * NEG + nn) * D;
      const float und = un[lane];
      const float un2 = wave_red(und * und);
      const float uun = wave_red(ud * und);
      const float xyn = -uun;
      const float c1 = 1.f + 2.f * xyn + un2;
      const float nd = c1 * (-ud) + co2 * und;  // co2 = 1 - u2 reused
      const float ns2 = wave_red(nd * nd);
      const float dn = fmaxf(1.f + 2.f * xyn + u2 * un2, EPS);
      const float rn = sqrtf(ns2) / dn;
      const float dsn = 2.f * atanhf(fminf(rn, BND));
      Z1 += expf(-dsn);
    }

    // hyperbolic angle at v
    const float norm_v = sqrtf(v2);
    const float euclid = sqrtf(e2);
    const float rad = fmaxf(1.f + u2 * v2 - 2.f * uv, EPS);
    const float den_a = fmaxf(norm_v * euclid * sqrtf(rad), EPS);
    const float cos_ang = (uv * (1.f + v2) - v2 * (1.f + u2)) / den_a;
    const float angle = acosf(fminf(fmaxf(cos_ang, -BND), BND));

    const float ns_loss = -logf(exp_neg / (Z1 + exp_neg));
    // alpha = 0.5: 2*(1-a)*angle + 2*a*ns = angle + ns
    local += angle + ns_loss;
  }

  if (lane == 0) wsums[w] = local;
  __syncthreads();
  if (t == 0) {
    float tot = 0.f;
    for (int k = 0; k < 16; ++k) tot += wsums[k];
    out[0] = tot / (float)B;
  }
}

extern "C" void kernel_launch(void* const* d_in, const int* in_sizes, int n_in,
                              void* d_out, int out_size, void* d_ws, size_t ws_size,
                              hipStream_t stream) {
  const float* encoded = (const float*)d_in[0];
  const float* n_encoded = (const float*)d_in[1];
  const float* mask1 = (const float*)d_in[2];
  const float* mask2 = (const float*)d_in[3];
  const float* mask_u_neg = (const float*)d_in[4];
  const float* W = (const float*)d_in[5];
  float* vecs = (float*)d_ws;  // NVEC * D floats = 98 KB

  gather_matvec_kernel<<<NVEC, 256, 0, stream>>>(
      encoded, n_encoded, mask1, mask2, mask_u_neg, W, vecs);
  loss_kernel<<<1, 1024, 0, stream>>>(vecs, (float*)d_out);
}

// Round 2
// 302.793 us; speedup vs baseline: 1.0070x; 1.0070x over previous
//
#include <hip/hip_runtime.h>
#include <math.h>

#define EPS 1e-15f
#define BND (1.0f - 1e-7f)

constexpr int B = 64, S = 256, H = 768, D = 64, NEG = 4;
constexpr int NVEC = B + B + B * NEG; // 384 selected vectors

// Reduce across a 64-lane wave; result broadcast to all lanes.
__device__ inline float wave_red(float v) {
#pragma unroll
  for (int o = 32; o > 0; o >>= 1) v += __shfl_down(v, o, 64);
  return __shfl(v, 0, 64);
}

__device__ inline float dot4(float4 a, float4 b) {
  return a.x * b.x + a.y * b.y + a.z * b.z + a.w * b.w;
}

// One block per selected vector: scan one-hot mask row -> gather encoded row
// -> expmap0 -> mobius_matvec(W, .) -> write [D] vector to workspace.
// W access is coalesced: wave w owns output rows d = w*16..w*16+15; lanes
// read consecutive float4s of each W row; xs is register-cached per wave.
__global__ __launch_bounds__(256) void gather_matvec_kernel(
    const float* __restrict__ encoded, const float* __restrict__ n_encoded,
    const float* __restrict__ mask1, const float* __restrict__ mask2,
    const float* __restrict__ mask_u_neg, const float* __restrict__ W,
    float* __restrict__ out_vecs) {
  __shared__ float xs[H];   // gathered raw row
  __shared__ float pm[D];   // matvec results per output dim
  __shared__ int s_idx;
  __shared__ float s_ssq;
  __shared__ float red[4];

  const int i = blockIdx.x;
  const int t = threadIdx.x;
  const int lane = t & 63, w = t >> 6;

  const float* mask;
  const float* src;
  if (i < B) {
    mask = mask1 + (size_t)i * S;
    src = encoded + (size_t)i * S * H;
  } else if (i < 2 * B) {
    mask = mask2 + (size_t)(i - B) * S;
    src = encoded + (size_t)(i - B) * S * H;
  } else {
    mask = mask_u_neg + (size_t)(i - 2 * B) * S;
    src = n_encoded + (size_t)(i - 2 * B) * S * H;
  }

  if (t == 0) s_idx = 0;
  __syncthreads();
  if (mask[t] > 0.5f) s_idx = t;  // one-hot: exactly one thread writes
  __syncthreads();
  const float* row = src + (size_t)s_idx * H;

  // Vectorized gather: 192 float4 = 768 floats. Threads 192..255 idle here.
  float ssq = 0.f;
  if (t < H / 4) {
    float4 v = ((const float4*)row)[t];
    ((float4*)xs)[t] = v;
    ssq = dot4(v, v);
  }
  float wsum = wave_red(ssq);
  if (lane == 0) red[w] = wsum;
  __syncthreads();
  if (t == 0) s_ssq = red[0] + red[1] + red[2] + red[3];
  __syncthreads();

  const float n = sqrtf(s_ssq);
  const float n_cl = fmaxf(n, EPS);
  const float scale0 = tanhf(n_cl) / n_cl;  // expmap0 scale

  // Register-cache this wave's view of xs (whole row, 3 float4/lane).
  const float4* xv = (const float4*)xs;
  const float4 x0 = xv[lane];
  const float4 x1 = xv[lane + 64];
  const float4 x2 = xv[lane + 128];

  // Wave w computes rows d = w*16 + r. Coalesced float4 reads of W.
  const float4* Wv = (const float4*)W;  // W[d][h] -> Wv[d*192 + j]
#pragma unroll 4
  for (int r = 0; r < 16; ++r) {
    const int d = w * 16 + r;
    const float4* wr = Wv + (size_t)d * (H / 4);
    float acc = dot4(x0, wr[lane]) + dot4(x1, wr[lane + 64]) +
                dot4(x2, wr[lane + 128]);
    float s = wave_red(acc);
    if (lane == 0) pm[d] = s;
  }
  __syncthreads();

  if (w == 0) {
    const int d = lane;
    float mx = pm[d] * scale0;
    float mnsq = wave_red(mx * mx);
    float mn = fmaxf(sqrtf(mnsq), EPS);
    float xn = fmaxf(scale0 * n, EPS);            // ||expmap0(x)|| = tanh(n)
    float xn_c = fminf(fmaxf(xn, -BND), BND);
    float arg = mn / xn * atanhf(xn_c);
    float s1 = tanhf(arg) / mn;
    out_vecs[(size_t)i * D + d] = s1 * mx;
  }
}

// Single block: wave w handles rows b = w, w+16, ...; lane = dim d.
__global__ __launch_bounds__(1024) void loss_kernel(
    const float* __restrict__ vecs, float* __restrict__ out) {
  __shared__ float wsums[16];
  const int t = threadIdx.x, lane = t & 63, w = t >> 6;
  float local = 0.f;

  for (int b = w; b < B; b += 16) {
    const float* u = vecs + (size_t)b * D;
    const float* v = vecs + (size_t)(B + b) * D;
    const float ud = u[lane], vd = v[lane];
    const float u2 = wave_red(ud * ud);
    const float v2 = wave_red(vd * vd);
    const float uv = wave_red(ud * vd);
    const float e2 = wave_red((ud - vd) * (ud - vd));

    // dist(u, v) = 2*artanh(||mobius_add(-u, v)||)
    const float xy = -uv;
    const float co1 = 1.f + 2.f * xy + v2;
    const float co2 = 1.f - u2;
    const float numd = co1 * (-ud) + co2 * vd;
    const float nsq = wave_red(numd * numd);
    const float den = fmaxf(1.f + 2.f * xy + u2 * v2, EPS);
    const float r = sqrtf(nsq) / den;
    const float dsq = 2.f * atanhf(fminf(r, BND));
    const float exp_neg = expf(-dsq);

    float Z1 = 0.f;
    for (int nn = 0; nn < NEG; ++nn) {
      const float* un = vecs + (size_t)(2 * B + b * NEG + nn) * D;
      const float und = un[lane];
      const float un2 = wave_red(und * und);
      const float uun = wave_red(ud * und);
      const float xyn = -uun;
      const float c1 = 1.f + 2.f * xyn + un2;
      const float nd = c1 * (-ud) + co2 * und;  // co2 = 1 - u2 reused
      const float ns2 = wave_red(nd * nd);
      const float dn = fmaxf(1.f + 2.f * xyn + u2 * un2, EPS);
      const float rn = sqrtf(ns2) / dn;
      const float dsn = 2.f * atanhf(fminf(rn, BND));
      Z1 += expf(-dsn);
    }

    // hyperbolic angle at v
    const float norm_v = sqrtf(v2);
    const float euclid = sqrtf(e2);
    const float rad = fmaxf(1.f + u2 * v2 - 2.f * uv, EPS);
    const float den_a = fmaxf(norm_v * euclid * sqrtf(rad), EPS);
    const float cos_ang = (uv * (1.f + v2) - v2 * (1.f + u2)) / den_a;
    const float angle = acosf(fminf(fmaxf(cos_ang, -BND), BND));

    const float ns_loss = -logf(exp_neg / (Z1 + exp_neg));
    // alpha = 0.5: 2*(1-a)*angle + 2*a*ns = angle + ns
    local += angle + ns_loss;
  }

  if (lane == 0) wsums[w] = local;
  __syncthreads();
  if (t == 0) {
    float tot = 0.f;
    for (int k = 0; k < 16; ++k) tot += wsums[k];
    out[0] = tot / (float)B;
  }
}

extern "C" void kernel_launch(void* const* d_in, const int* in_sizes, int n_in,
                              void* d_out, int out_size, void* d_ws, size_t ws_size,
                              hipStream_t stream) {
  const float* encoded = (const float*)d_in[0];
  const float* n_encoded = (const float*)d_in[1];
  const float* mask1 = (const float*)d_in[2];
  const float* mask2 = (const float*)d_in[3];
  const float* mask_u_neg = (const float*)d_in[4];
  const float* W = (const float*)d_in[5];
  float* vecs = (float*)d_ws;  // NVEC * D floats = 98 KB

  gather_matvec_kernel<<<NVEC, 256, 0, stream>>>(
      encoded, n_encoded, mask1, mask2, mask_u_neg, W, vecs);
  loss_kernel<<<1, 1024, 0, stream>>>(vecs, (float*)d_out);
}